// Round 1
// 4037.764 us; speedup vs baseline: 2.1320x; 2.1320x over previous
//
#include <hip/hip_runtime.h>

// ---------------- problem constants ----------------
#define TOKENS   65536      // B*N = 32*2048
#define DDIM     512
#define NQ       8
#define NCODES   1024
#define COMMIT_W 0.02

// ---------------- tiling ----------------
#define MT       32         // tokens per block
#define NBLOCKS  (TOKENS / MT)   // 2048
#define KSPLIT   384        // OpenBLAS sgemm K-panel split (SGEMM_DEFAULT_Q)

// out buffer layout (fp32 elements): [quantized][indices][losses][total]
#define OFF_IDX  ((size_t)TOKENS * DDIM)
#define OFF_LOSS (OFF_IDX + (size_t)TOKENS * NQ)
#define OFF_TOT  (OFF_LOSS + NQ)

typedef _Float16 f16;
typedef _Float16 f16x8 __attribute__((ext_vector_type(8)));
typedef float    f32x4 __attribute__((ext_vector_type(4)));

__device__ __forceinline__ bool better(float d, int i, float bd, int bi) {
  return (d < bd) || (d == bd && i < bi);
}

// sorted-4 insert (ascending, index tiebreak). Fully inlined, const indices.
__device__ __forceinline__ void ins4(float dd, int c, float cd[4], int ci[4]) {
  if (better(dd, c, cd[3], ci[3])) {
    if (better(dd, c, cd[1], ci[1])) {
      if (better(dd, c, cd[0], ci[0])) {
        cd[3]=cd[2]; ci[3]=ci[2]; cd[2]=cd[1]; ci[2]=ci[1];
        cd[1]=cd[0]; ci[1]=ci[0]; cd[0]=dd; ci[0]=c;
      } else {
        cd[3]=cd[2]; ci[3]=ci[2]; cd[2]=cd[1]; ci[2]=ci[1];
        cd[1]=dd; ci[1]=c;
      }
    } else {
      if (better(dd, c, cd[2], ci[2])) { cd[3]=cd[2]; ci[3]=ci[2]; cd[2]=dd; ci[2]=c; }
      else { cd[3]=dd; ci[3]=c; }
    }
  }
}

// bitonic merge of two sorted-4 lists across lanes (xor mask m), keep lower 4
__device__ __forceinline__ void merge4(float cd[4], int ci[4], const int m) {
  const float b0 = __shfl_xor(cd[0], m, 64), b1 = __shfl_xor(cd[1], m, 64),
              b2 = __shfl_xor(cd[2], m, 64), b3 = __shfl_xor(cd[3], m, 64);
  const int   o0 = __shfl_xor(ci[0], m, 64), o1 = __shfl_xor(ci[1], m, 64),
              o2 = __shfl_xor(ci[2], m, 64), o3 = __shfl_xor(ci[3], m, 64);
  float L0, L1, L2, L3; int M0, M1, M2, M3;
  if (better(b3, o3, cd[0], ci[0])) { L0 = b3; M0 = o3; } else { L0 = cd[0]; M0 = ci[0]; }
  if (better(b2, o2, cd[1], ci[1])) { L1 = b2; M1 = o2; } else { L1 = cd[1]; M1 = ci[1]; }
  if (better(b1, o1, cd[2], ci[2])) { L2 = b1; M2 = o1; } else { L2 = cd[2]; M2 = ci[2]; }
  if (better(b0, o0, cd[3], ci[3])) { L3 = b0; M3 = o0; } else { L3 = cd[3]; M3 = ci[3]; }
  if (better(L2, M2, L0, M0)) { float t=L0; L0=L2; L2=t; int u=M0; M0=M2; M2=u; }
  if (better(L3, M3, L1, M1)) { float t=L1; L1=L3; L3=t; int u=M1; M1=M3; M3=u; }
  if (better(L1, M1, L0, M0)) { float t=L0; L0=L1; L1=t; int u=M0; M0=M1; M1=u; }
  if (better(L3, M3, L2, M2)) { float t=L2; L2=L3; L3=t; int u=M2; M2=M3; M3=u; }
  cd[0]=L0; ci[0]=M0; cd[1]=L1; ci[1]=M1; cd[2]=L2; ci[2]=M2; cd[3]=L3; ci[3]=M3;
}

// numpy pairwise leaf: 8-accumulator sum of fl(a[k]^2), n=128, row-major
__device__ __forceinline__ float pw128_row_sq(const float* __restrict__ a) {
  float r0 = __fmul_rn(a[0], a[0]), r1 = __fmul_rn(a[1], a[1]);
  float r2 = __fmul_rn(a[2], a[2]), r3 = __fmul_rn(a[3], a[3]);
  float r4 = __fmul_rn(a[4], a[4]), r5 = __fmul_rn(a[5], a[5]);
  float r6 = __fmul_rn(a[6], a[6]), r7 = __fmul_rn(a[7], a[7]);
  for (int i = 8; i < 128; i += 8) {
    r0 = __fadd_rn(r0, __fmul_rn(a[i + 0], a[i + 0]));
    r1 = __fadd_rn(r1, __fmul_rn(a[i + 1], a[i + 1]));
    r2 = __fadd_rn(r2, __fmul_rn(a[i + 2], a[i + 2]));
    r3 = __fadd_rn(r3, __fmul_rn(a[i + 3], a[i + 3]));
    r4 = __fadd_rn(r4, __fmul_rn(a[i + 4], a[i + 4]));
    r5 = __fadd_rn(r5, __fmul_rn(a[i + 5], a[i + 5]));
    r6 = __fadd_rn(r6, __fmul_rn(a[i + 6], a[i + 6]));
    r7 = __fadd_rn(r7, __fmul_rn(a[i + 7], a[i + 7]));
  }
  return __fadd_rn(__fadd_rn(__fadd_rn(r0, r1), __fadd_rn(r2, r3)),
                   __fadd_rn(__fadd_rn(r4, r5), __fadd_rn(r6, r7)));
}

// ---------------- prep: ee = np-pairwise fp32 ||e||^2 + zero loss accumulators ----
__global__ void prep_kernel(const float* __restrict__ cb, float* __restrict__ eef,
                            double* __restrict__ lossAcc) {
  const int code = blockIdx.x * blockDim.x + threadIdx.x;   // 32 x 256 = 8192
  if (code == 0) {
#pragma unroll
    for (int j = 0; j < NQ; ++j) lossAcc[j] = 0.0;
  }
  if (code < NQ * NCODES) {
    const float* e = cb + (size_t)code * DDIM;
    const float p0 = pw128_row_sq(e), p1 = pw128_row_sq(e + 128);
    const float p2 = pw128_row_sq(e + 256), p3 = pw128_row_sq(e + 384);
    eef[code] = __fadd_rn(__fadd_rn(p0, p1), __fadd_rn(p2, p3));  // np pw512 tree
  }
}

// ---------------- codebook fp32 -> f16 (screen operand; RNE) ----------------
__global__ void cvt_kernel(const float* __restrict__ cb, f16* __restrict__ cbH) {
  const size_t base = ((size_t)blockIdx.x * 256 + threadIdx.x) * 8;  // 2048*256*8 == NQ*NCODES*DDIM
  const float4 v0 = *(const float4*)(cb + base);
  const float4 v1 = *(const float4*)(cb + base + 4);
  f16x8 h;
  h[0] = (f16)v0.x; h[1] = (f16)v0.y; h[2] = (f16)v0.z; h[3] = (f16)v0.w;
  h[4] = (f16)v1.x; h[5] = (f16)v1.y; h[6] = (f16)v1.z; h[7] = (f16)v1.w;
  *(f16x8*)(cbH + base) = h;
}

// ---------------- main fused RVQ kernel ----------------
// One block owns MT=32 tokens through all 8 rounds.
//  - faithful np-fp32 residual chain lives (transposed) in LDS (r_t)
//  - SCREEN is now f16 MFMA (16x16x32): A = codebook tile (wave owns 256 codes,
//    16 M-tiles), B = residual f16 (2 N-tiles of 16 tokens). Screen noise
//    sigma ~0.03 << top-4 distance gaps O(10) -> true argmin stays in top-4.
//  - per-wave sorted-4 lists -> 2-step cross-lane merge -> 4 waves x top-4 in
//    LDS -> global top-4 -> np-faithful fp32 rescore (unchanged from previous
//    version) -> residual update / loss / replay unchanged (bit-exact path).
__global__ void __launch_bounds__(256, 2)
rvq_main(const float* __restrict__ x, const float* __restrict__ cb,
         const f16* __restrict__ cbH, const float* __restrict__ eef,
         double* __restrict__ lossAcc, float* __restrict__ outq,
         float* __restrict__ outidx) {
  __shared__ float  r_t[DDIM * MT];                 // 64 KB, residual transposed [k][tm]
  __shared__ __align__(16) char smem_u[MT * 128 * 2];  // 8 KB union: ra (f16 k-chunk) | wcd+wci
  __shared__ float  ee_lds[NCODES];                 // 4 KB, this round's ||e||^2
  __shared__ int    hist[MT][NQ];                   // 1 KB
  __shared__ double wred[4];

  f16*   ra  = (f16*)smem_u;            // [tok][128] f16, XOR-swizzled, one 128-K chunk
  float* wcd = (float*)smem_u;          // [wave][32 tok][4] screen dists
  int*   wci = (int*)(smem_u + 2048);   // [wave][32 tok][4] screen codes

  const int tid  = threadIdx.x;
  const int lane = tid & 63;
  const int wv   = tid >> 6;            // wave id: owns codes [wv*256, wv*256+256)
  const int cbase = wv << 8;
  const int tokR = tid >> 3;            // update mapping: token
  const int part = tid & 7;             //   ... and its 1/8 slice of D
  const int blockTok = blockIdx.x * MT;

  // ---- phase 0: load x tile -> transposed fp32 residual cache (bit-exact copy) ----
  {
    const int tm = tid & 31, kp = tid >> 5;
    const float* xr = x + (size_t)(blockTok + tm) * DDIM;
#pragma unroll
    for (int i = 0; i < 16; ++i) {
      const int d4 = (kp + i * 8) << 2;
      const float4 v = *(const float4*)(xr + d4);
      r_t[(d4 + 0) * MT + tm] = v.x;
      r_t[(d4 + 1) * MT + tm] = v.y;
      r_t[(d4 + 2) * MT + tm] = v.z;
      r_t[(d4 + 3) * MT + tm] = v.w;
    }
  }
  __syncthreads();

  const int la15 = lane & 15;
  const int kg8  = (lane >> 4) << 3;        // lane's 8-elem k-group within K=32
  const int swz  = (la15 & 7) << 3;         // f16-index XOR swizzle for B reads

  for (int qi = 0; qi < NQ; ++qi) {
    const float* cbq   = cb  + (size_t)qi * NCODES * DDIM;
    const f16*   cbq16 = cbH + (size_t)qi * NCODES * DDIM;
    const float* enq   = eef + qi * NCODES;

    // stage this round's ee into LDS (read at selection, after chunk barriers)
#pragma unroll
    for (int j = 0; j < 4; ++j) ee_lds[tid + j * 256] = enq[tid + j * 256];

    // accumulators: 16 M-tiles (codes) x 2 N-tiles (tokens), f32x4 each
    f32x4 acc[16][2];
#pragma unroll
    for (int mt = 0; mt < 16; ++mt) {
      acc[mt][0] = (f32x4){0.f, 0.f, 0.f, 0.f};
      acc[mt][1] = (f32x4){0.f, 0.f, 0.f, 0.f};
    }

    // ---- screen: 4 chunks of K=128; convert residual slice -> f16 LDS, MFMA ----
    for (int ch = 0; ch < 4; ++ch) {
      __syncthreads();  // ra region free (prev chunk MFMA done / prev round wcd done)
      {
        const int tok  = tid & 31;
        const int ko   = tid >> 5;
        const int tswz = (tok & 7) << 3;
#pragma unroll
        for (int i = 0; i < 2; ++i) {
          const int kl = (ko + (i << 3)) << 3;     // local k octet base 0..120
          const int kg = (ch << 7) + kl;           // global k
          f16x8 h;
#pragma unroll
          for (int j = 0; j < 8; ++j) h[j] = (f16)r_t[(kg + j) * MT + tok];
          *(f16x8*)&ra[tok * 128 + (kl ^ tswz)] = h;
        }
      }
      __syncthreads();
#pragma unroll
      for (int s = 0; s < 4; ++s) {
        const int kk = (s << 5) + kg8;             // local k of this lane's group
        const f16x8 b0 = *(const f16x8*)&ra[la15 * 128 + (kk ^ swz)];
        const f16x8 b1 = *(const f16x8*)&ra[(la15 + 16) * 128 + (kk ^ swz)];
        const f16* ap = cbq16 + (size_t)(cbase + la15) * DDIM + (ch << 7) + kk;
#pragma unroll
        for (int mt = 0; mt < 16; ++mt) {
          const f16x8 a = *(const f16x8*)(ap + (size_t)(mt << 4) * DDIM);
          acc[mt][0] = __builtin_amdgcn_mfma_f32_16x16x32_f16(a, b0, acc[mt][0], 0, 0, 0);
          acc[mt][1] = __builtin_amdgcn_mfma_f32_16x16x32_f16(a, b1, acc[mt][1], 0, 0, 0);
        }
      }
    }
    __syncthreads();  // all waves done reading ra before wcd overwrite (union!)

    // ---- per-lane sorted-4 over this lane's 64 codes x 2 tokens ----
    float cd0[4], cd1[4]; int ci0[4], ci1[4];
#pragma unroll
    for (int s = 0; s < 4; ++s) {
      cd0[s] = 3.0e38f; ci0[s] = 0x7fffffff;
      cd1[s] = 3.0e38f; ci1[s] = 0x7fffffff;
    }
    const int rbase = cbase + ((lane >> 4) << 2);
#pragma unroll
    for (int mt = 0; mt < 16; ++mt) {
#pragma unroll
      for (int r = 0; r < 4; ++r) {
        const int code = rbase + (mt << 4) + r;
        const float eb = ee_lds[code];
        ins4(fmaf(-2.0f, acc[mt][0][r], eb), code, cd0, ci0);  // token la15
        ins4(fmaf(-2.0f, acc[mt][1][r], eb), code, cd1, ci1);  // token la15+16
      }
    }
    // merge across the 4 row-groups sharing each token (xor 16, 32)
    merge4(cd0, ci0, 16); merge4(cd0, ci0, 32);
    merge4(cd1, ci1, 16); merge4(cd1, ci1, 32);

    if (lane < 16) {
      const int w32 = wv << 5;
#pragma unroll
      for (int s = 0; s < 4; ++s) {
        wcd[(w32 + lane) * 4 + s]      = cd0[s];
        wci[(w32 + lane) * 4 + s]      = ci0[s];
        wcd[(w32 + lane + 16) * 4 + s] = cd1[s];
        wci[(w32 + lane + 16) * 4 + s] = ci1[s];
      }
    }
    __syncthreads();

    // ---- global top-4-of-16 then faithful np-fp32 rescore ----
    if (tid < 128) {
      const int tok4 = tid >> 2, cnd = tid & 3;
      float fd[4]; int fi[4];
#pragma unroll
      for (int s = 0; s < 4; ++s) { fd[s] = 3.0e38f; fi[s] = 0x7fffffff; }
      for (int w2 = 0; w2 < 4; ++w2) {
#pragma unroll
        for (int s = 0; s < 4; ++s) {
          const int e = ((w2 << 5) + tok4) * 4 + s;
          ins4(wcd[e], wci[e], fd, fi);
        }
      }
      const int cme = fi[cnd];

      // rr: numpy pairwise sum of fl(r*r) over 512 (tree: ((pw+pw)+(pw+pw)))
      float blk;
      {
        const int kb = cnd * 128;
        float a[8];
#pragma unroll
        for (int j = 0; j < 8; ++j) {
          const float v = r_t[(kb + j) * MT + tok4];
          a[j] = __fmul_rn(v, v);
        }
        for (int i = 8; i < 128; i += 8) {
#pragma unroll
          for (int j = 0; j < 8; ++j) {
            const float v = r_t[(kb + i + j) * MT + tok4];
            a[j] = __fadd_rn(a[j], __fmul_rn(v, v));
          }
        }
        blk = __fadd_rn(__fadd_rn(__fadd_rn(a[0], a[1]), __fadd_rn(a[2], a[3])),
                        __fadd_rn(__fadd_rn(a[4], a[5]), __fadd_rn(a[6], a[7])));
      }
      const float pw256 = __fadd_rn(blk, __shfl_xor(blk, 1, 64));
      const float rr    = __fadd_rn(pw256, __shfl_xor(pw256, 2, 64));

      // cross: sgemm-faithful sequential-k FMA chain, K split at KSPLIT
      const float* ep = cbq + (size_t)cme * DDIM;
      float Sa = 0.f, Sb = 0.f;
      for (int kb = 0; kb < DDIM; kb += 8) {
        const float4 e0 = *(const float4*)(ep + kb);
        const float4 e1 = *(const float4*)(ep + kb + 4);
        const float ev[8] = {e0.x, e0.y, e0.z, e0.w, e1.x, e1.y, e1.z, e1.w};
        float rv[8];
#pragma unroll
        for (int j = 0; j < 8; ++j) rv[j] = r_t[(kb + j) * MT + tok4];
        if (kb < KSPLIT) {
#pragma unroll
          for (int j = 0; j < 8; ++j) Sa = __fmaf_rn(rv[j], ev[j], Sa);
        } else {
#pragma unroll
          for (int j = 0; j < 8; ++j) Sb = __fmaf_rn(rv[j], ev[j], Sb);
        }
      }
      const float cross = __fadd_rn(Sa, Sb);
      const float u = __fsub_rn(rr, __fmul_rn(2.0f, cross));
      float dW = __fadd_rn(u, enq[cme]);
      int   cW = cme;
#pragma unroll
      for (int m = 1; m <= 2; m <<= 1) {
        const float od = __shfl_xor(dW, m, 64);
        const int   oc = __shfl_xor(cW, m, 64);
        if (better(od, oc, dW, cW)) { dW = od; cW = oc; }
      }
      if (cnd == 0) {
        hist[tok4][qi] = cW;
        outidx[(size_t)(blockTok + tok4) * NQ + qi] = (float)cW;
      }
    }
    __syncthreads();

    // ---- faithful fp32 residual update + commit-loss sum ----
    const int wc = hist[tokR][qi];
    const float* ew = cbq + (size_t)wc * DDIM;
    double lssq = 0.0;
    for (int i = 0; i < 16; ++i) {
      const int d4 = (part + i * 8) << 2;
      const float4 qv = *(const float4*)(ew + d4);
      const float qa[4] = {qv.x, qv.y, qv.z, qv.w};
#pragma unroll
      for (int e = 0; e < 4; ++e) {
        const float r  = r_t[(d4 + e) * MT + tokR];
        const float a  = __fsub_rn(qa[e], r);       // fl(q - r)   (commit diff)
        const float qs = __fadd_rn(r, a);           // q_st = fl(r + (q-r))
        const float rn = __fsub_rn(r, qs);          // r' = fl(r - q_st)
        r_t[(d4 + e) * MT + tokR] = rn;
        lssq += (double)a * (double)a;
      }
    }
#pragma unroll
    for (int off = 32; off; off >>= 1) lssq += __shfl_down(lssq, off, 64);
    if ((tid & 63) == 0) wred[tid >> 6] = lssq;
    __syncthreads();
    if (tid == 0) atomicAdd(&lossAcc[qi], wred[0] + wred[1] + wred[2] + wred[3]);
  } // qi

  // ---- final: faithful fp32 replay -> quantized_out = sum of q_st per round ----
  {
    for (int i = 0; i < 16; ++i) {
      const int d4 = (part + i * 8) << 2;
      const float4 xv = *(const float4*)(x + (size_t)(blockTok + tokR) * DDIM + d4);
      float r[4]  = {xv.x, xv.y, xv.z, xv.w};
      float qa[4] = {0.f, 0.f, 0.f, 0.f};
#pragma unroll
      for (int j = 0; j < NQ; ++j) {
        const int hj = hist[tokR][j];
        const float4 ev = *(const float4*)(cb + ((size_t)j * NCODES + hj) * DDIM + d4);
        const float qv[4] = {ev.x, ev.y, ev.z, ev.w};
#pragma unroll
        for (int e = 0; e < 4; ++e) {
          const float a  = __fsub_rn(qv[e], r[e]);
          const float qs = __fadd_rn(r[e], a);
          r[e]  = __fsub_rn(r[e], qs);
          qa[e] = __fadd_rn(qa[e], qs);
        }
      }
      float4 pk; pk.x = qa[0]; pk.y = qa[1]; pk.z = qa[2]; pk.w = qa[3];
      *(float4*)(outq + (size_t)(blockTok + tokR) * DDIM + d4) = pk;
    }
  }
}

// ---------------- losses finalize ----------------
__global__ void loss_fin(const double* __restrict__ lossAcc,
                         float* __restrict__ outLoss,
                         float* __restrict__ outTot) {
  if (threadIdx.x == 0 && blockIdx.x == 0) {
    double tot = 0.0;
    for (int qi = 0; qi < NQ; ++qi) {
      const double v = lossAcc[qi] * (COMMIT_W / ((double)TOKENS * (double)DDIM));
      outLoss[qi] = (float)v;
      tot += v;
    }
    *outTot = (float)tot;
  }
}

extern "C" void kernel_launch(void* const* d_in, const int* in_sizes, int n_in,
                              void* d_out, int out_size, void* d_ws, size_t ws_size,
                              hipStream_t stream) {
  const float* x  = (const float*)d_in[0];
  const float* cb = (const float*)d_in[1];
  float* out = (float*)d_out;

  // workspace layout: [0..64) lossAcc f64 x8 | [256..33024) eef | [64K..64K+8M) f16 codebook
  double* lossAcc = (double*)d_ws;
  float*  eef     = (float*)((char*)d_ws + 256);
  f16*    cbH     = (f16*)((char*)d_ws + 65536);

  prep_kernel<<<dim3(32), dim3(256), 0, stream>>>(cb, eef, lossAcc);
  cvt_kernel<<<dim3(2048), dim3(256), 0, stream>>>(cb, cbH);
  rvq_main<<<dim3(NBLOCKS), dim3(256), 0, stream>>>(x, cb, cbH, eef, lossAcc,
                                                    out, out + OFF_IDX);
  loss_fin<<<dim3(1), dim3(64), 0, stream>>>(lossAcc, out + OFF_LOSS, out + OFF_TOT);
}

// Round 2
// 3462.173 us; speedup vs baseline: 2.4864x; 1.1663x over previous
//
#include <hip/hip_runtime.h>

// ---------------- problem constants ----------------
#define TOKENS   65536      // B*N = 32*2048
#define DDIM     512
#define NQ       8
#define NCODES   1024
#define COMMIT_W 0.02

// ---------------- tiling ----------------
#define MT       32         // tokens per block
#define NT       512        // threads per block (8 waves)
#define NBLOCKS  (TOKENS / MT)   // 2048
#define KSPLIT   384        // OpenBLAS sgemm K-panel split (SGEMM_DEFAULT_Q)

// out buffer layout (fp32 elements): [quantized][indices][losses][total]
#define OFF_IDX  ((size_t)TOKENS * DDIM)
#define OFF_LOSS (OFF_IDX + (size_t)TOKENS * NQ)
#define OFF_TOT  (OFF_LOSS + NQ)

typedef _Float16 f16;
typedef _Float16 f16x8 __attribute__((ext_vector_type(8)));
typedef float    f32x4 __attribute__((ext_vector_type(4)));

__device__ __forceinline__ bool better(float d, int i, float bd, int bi) {
  return (d < bd) || (d == bd && i < bi);
}

// sorted-4 insert (ascending, index tiebreak). Fully inlined, const indices.
__device__ __forceinline__ void ins4(float dd, int c, float cd[4], int ci[4]) {
  if (better(dd, c, cd[3], ci[3])) {
    if (better(dd, c, cd[1], ci[1])) {
      if (better(dd, c, cd[0], ci[0])) {
        cd[3]=cd[2]; ci[3]=ci[2]; cd[2]=cd[1]; ci[2]=ci[1];
        cd[1]=cd[0]; ci[1]=ci[0]; cd[0]=dd; ci[0]=c;
      } else {
        cd[3]=cd[2]; ci[3]=ci[2]; cd[2]=cd[1]; ci[2]=ci[1];
        cd[1]=dd; ci[1]=c;
      }
    } else {
      if (better(dd, c, cd[2], ci[2])) { cd[3]=cd[2]; ci[3]=ci[2]; cd[2]=dd; ci[2]=c; }
      else { cd[3]=dd; ci[3]=c; }
    }
  }
}

// bitonic merge of two sorted-4 lists across lanes (xor mask m), keep lower 4
__device__ __forceinline__ void merge4(float cd[4], int ci[4], const int m) {
  const float b0 = __shfl_xor(cd[0], m, 64), b1 = __shfl_xor(cd[1], m, 64),
              b2 = __shfl_xor(cd[2], m, 64), b3 = __shfl_xor(cd[3], m, 64);
  const int   o0 = __shfl_xor(ci[0], m, 64), o1 = __shfl_xor(ci[1], m, 64),
              o2 = __shfl_xor(ci[2], m, 64), o3 = __shfl_xor(ci[3], m, 64);
  float L0, L1, L2, L3; int M0, M1, M2, M3;
  if (better(b3, o3, cd[0], ci[0])) { L0 = b3; M0 = o3; } else { L0 = cd[0]; M0 = ci[0]; }
  if (better(b2, o2, cd[1], ci[1])) { L1 = b2; M1 = o2; } else { L1 = cd[1]; M1 = ci[1]; }
  if (better(b1, o1, cd[2], ci[2])) { L2 = b1; M2 = o1; } else { L2 = cd[2]; M2 = ci[2]; }
  if (better(b0, o0, cd[3], ci[3])) { L3 = b0; M3 = o0; } else { L3 = cd[3]; M3 = ci[3]; }
  if (better(L2, M2, L0, M0)) { float t=L0; L0=L2; L2=t; int u=M0; M0=M2; M2=u; }
  if (better(L3, M3, L1, M1)) { float t=L1; L1=L3; L3=t; int u=M1; M1=M3; M3=u; }
  if (better(L1, M1, L0, M0)) { float t=L0; L0=L1; L1=t; int u=M0; M0=M1; M1=u; }
  if (better(L3, M3, L2, M2)) { float t=L2; L2=L3; L3=t; int u=M2; M2=M3; M3=u; }
  cd[0]=L0; ci[0]=M0; cd[1]=L1; ci[1]=M1; cd[2]=L2; ci[2]=M2; cd[3]=L3; ci[3]=M3;
}

// numpy pairwise leaf: 8-accumulator sum of fl(a[k]^2), n=128, row-major
__device__ __forceinline__ float pw128_row_sq(const float* __restrict__ a) {
  float r0 = __fmul_rn(a[0], a[0]), r1 = __fmul_rn(a[1], a[1]);
  float r2 = __fmul_rn(a[2], a[2]), r3 = __fmul_rn(a[3], a[3]);
  float r4 = __fmul_rn(a[4], a[4]), r5 = __fmul_rn(a[5], a[5]);
  float r6 = __fmul_rn(a[6], a[6]), r7 = __fmul_rn(a[7], a[7]);
  for (int i = 8; i < 128; i += 8) {
    r0 = __fadd_rn(r0, __fmul_rn(a[i + 0], a[i + 0]));
    r1 = __fadd_rn(r1, __fmul_rn(a[i + 1], a[i + 1]));
    r2 = __fadd_rn(r2, __fmul_rn(a[i + 2], a[i + 2]));
    r3 = __fadd_rn(r3, __fmul_rn(a[i + 3], a[i + 3]));
    r4 = __fadd_rn(r4, __fmul_rn(a[i + 4], a[i + 4]));
    r5 = __fadd_rn(r5, __fmul_rn(a[i + 5], a[i + 5]));
    r6 = __fadd_rn(r6, __fmul_rn(a[i + 6], a[i + 6]));
    r7 = __fadd_rn(r7, __fmul_rn(a[i + 7], a[i + 7]));
  }
  return __fadd_rn(__fadd_rn(__fadd_rn(r0, r1), __fadd_rn(r2, r3)),
                   __fadd_rn(__fadd_rn(r4, r5), __fadd_rn(r6, r7)));
}

// ---------------- prep: ee = np-pairwise fp32 ||e||^2 + zero loss accumulators ----
__global__ void prep_kernel(const float* __restrict__ cb, float* __restrict__ eef,
                            double* __restrict__ lossAcc) {
  const int code = blockIdx.x * blockDim.x + threadIdx.x;   // 32 x 256 = 8192
  if (code == 0) {
#pragma unroll
    for (int j = 0; j < NQ; ++j) lossAcc[j] = 0.0;
  }
  if (code < NQ * NCODES) {
    const float* e = cb + (size_t)code * DDIM;
    const float p0 = pw128_row_sq(e), p1 = pw128_row_sq(e + 128);
    const float p2 = pw128_row_sq(e + 256), p3 = pw128_row_sq(e + 384);
    eef[code] = __fadd_rn(__fadd_rn(p0, p1), __fadd_rn(p2, p3));  // np pw512 tree
  }
}

// ---------------- codebook fp32 -> f16 (screen operand; RNE) ----------------
__global__ void cvt_kernel(const float* __restrict__ cb, f16* __restrict__ cbH) {
  const size_t base = ((size_t)blockIdx.x * 256 + threadIdx.x) * 8;  // 2048*256*8 == NQ*NCODES*DDIM
  const float4 v0 = *(const float4*)(cb + base);
  const float4 v1 = *(const float4*)(cb + base + 4);
  f16x8 h;
  h[0] = (f16)v0.x; h[1] = (f16)v0.y; h[2] = (f16)v0.z; h[3] = (f16)v0.w;
  h[4] = (f16)v1.x; h[5] = (f16)v1.y; h[6] = (f16)v1.z; h[7] = (f16)v1.w;
  *(f16x8*)(cbH + base) = h;
}

// ---------------- main fused RVQ kernel ----------------
// One block (512 threads, 8 waves) owns MT=32 tokens through all 8 rounds.
//  - faithful np-fp32 residual chain lives (transposed, k-major) in LDS (r_t)
//  - SCREEN: f16 MFMA 16x16x32; each wave owns 128 codes (8 M-tiles) x 32
//    tokens (2 N-tiles). Residual converted per-128-K-chunk into a swizzled
//    f16 LDS slab (ra). Screen noise sigma ~0.03 << top-4 gaps O(10).
//  - per-wave sorted-4 -> cross-lane merge -> 8 waves x top-4 in LDS ->
//    global top-4 -> np-faithful fp32 rescore (bit-exact path, unchanged).
//  - residual update remapped to (tok = tid&31, kslab = tid>>5): each 32-lane
//    phase group covers all 32 LDS banks exactly once -> conflict-free.
__global__ void __launch_bounds__(NT, 4)
rvq_main(const float* __restrict__ x, const float* __restrict__ cb,
         const f16* __restrict__ cbH, const float* __restrict__ eef,
         double* __restrict__ lossAcc, float* __restrict__ outq,
         float* __restrict__ outidx) {
  __shared__ float  r_t[DDIM * MT];                 // 64 KB, residual transposed [k][tm]
  __shared__ __align__(16) char smem_u[8192];       // 8 KB union: ra (f16 k-chunk) | wcd+wci
  __shared__ float  ee_lds[NCODES];                 // 4 KB, this round's ||e||^2
  __shared__ int    hist[MT][NQ];                   // 1 KB
  __shared__ double wred[8];

  f16*   ra  = (f16*)smem_u;            // [tok][128] f16, XOR-swizzled, one 128-K chunk
  float* wcd = (float*)smem_u;          // [8 wave][32 tok][4] screen dists (4 KB)
  int*   wci = (int*)(smem_u + 4096);   // [8 wave][32 tok][4] screen codes  (4 KB)

  const int tid  = threadIdx.x;
  const int lane = tid & 63;
  const int wv   = tid >> 6;            // wave id 0..7: owns codes [wv*128, wv*128+128)
  const int cbase = wv << 7;
  const int blockTok = blockIdx.x * MT;

  // ---- phase 0: load x tile -> transposed fp32 residual cache (bit-exact copy) ----
  {
    const int tm = tid & 31, kp = tid >> 5;          // kp 0..15
    const float* xr = x + (size_t)(blockTok + tm) * DDIM;
#pragma unroll
    for (int i = 0; i < 8; ++i) {
      const int d4 = (kp + i * 16) << 2;
      const float4 v = *(const float4*)(xr + d4);
      r_t[(d4 + 0) * MT + tm] = v.x;
      r_t[(d4 + 1) * MT + tm] = v.y;
      r_t[(d4 + 2) * MT + tm] = v.z;
      r_t[(d4 + 3) * MT + tm] = v.w;
    }
  }
  __syncthreads();

  const int la15 = lane & 15;
  const int kg8  = (lane >> 4) << 3;        // lane's 8-elem k-group within K=32
  const int swz  = (la15 & 7) << 3;         // f16-index XOR swizzle for B reads

  for (int qi = 0; qi < NQ; ++qi) {
    const float* cbq   = cb  + (size_t)qi * NCODES * DDIM;
    const f16*   cbq16 = cbH + (size_t)qi * NCODES * DDIM;
    const float* enq   = eef + qi * NCODES;

    // stage this round's ee into LDS (read at selection, after chunk barriers)
#pragma unroll
    for (int j = 0; j < 2; ++j) ee_lds[tid + j * NT] = enq[tid + j * NT];

    // accumulators: 8 M-tiles (codes) x 2 N-tiles (tokens), f32x4 each
    f32x4 acc[8][2];
#pragma unroll
    for (int mt = 0; mt < 8; ++mt) {
      acc[mt][0] = (f32x4){0.f, 0.f, 0.f, 0.f};
      acc[mt][1] = (f32x4){0.f, 0.f, 0.f, 0.f};
    }

    // ---- screen: 4 chunks of K=128; convert residual slice -> f16 LDS, MFMA ----
    for (int ch = 0; ch < 4; ++ch) {
      __syncthreads();  // ra region free (prev chunk MFMA done / prev round wcd done)
      {
        const int tok  = tid & 31;
        const int ko   = tid >> 5;               // 0..15
        const int tswz = (tok & 7) << 3;
        const int kl   = ko << 3;                // local k octet base 0..120
        const int kg   = (ch << 7) + kl;         // global k
        f16x8 h;
#pragma unroll
        for (int j = 0; j < 8; ++j) h[j] = (f16)r_t[(kg + j) * MT + tok];
        *(f16x8*)&ra[tok * 128 + (kl ^ tswz)] = h;
      }
      __syncthreads();
#pragma unroll
      for (int s = 0; s < 4; ++s) {
        const int kk = (s << 5) + kg8;           // local k of this lane's group
        const f16x8 b0 = *(const f16x8*)&ra[la15 * 128 + (kk ^ swz)];
        const f16x8 b1 = *(const f16x8*)&ra[(la15 + 16) * 128 + (kk ^ swz)];
        const f16* ap = cbq16 + (size_t)(cbase + la15) * DDIM + (ch << 7) + kk;
#pragma unroll
        for (int mt = 0; mt < 8; ++mt) {
          const f16x8 a = *(const f16x8*)(ap + (size_t)(mt << 4) * DDIM);
          acc[mt][0] = __builtin_amdgcn_mfma_f32_16x16x32_f16(a, b0, acc[mt][0], 0, 0, 0);
          acc[mt][1] = __builtin_amdgcn_mfma_f32_16x16x32_f16(a, b1, acc[mt][1], 0, 0, 0);
        }
      }
    }
    __syncthreads();  // all waves done reading ra before wcd overwrite (union!)

    // ---- per-lane sorted-4 over this lane's 32 codes x 2 tokens ----
    float cd0[4], cd1[4]; int ci0[4], ci1[4];
#pragma unroll
    for (int s = 0; s < 4; ++s) {
      cd0[s] = 3.0e38f; ci0[s] = 0x7fffffff;
      cd1[s] = 3.0e38f; ci1[s] = 0x7fffffff;
    }
    const int rbase = cbase + ((lane >> 4) << 2);
#pragma unroll
    for (int mt = 0; mt < 8; ++mt) {
#pragma unroll
      for (int r = 0; r < 4; ++r) {
        const int code = rbase + (mt << 4) + r;
        const float eb = ee_lds[code];
        ins4(fmaf(-2.0f, acc[mt][0][r], eb), code, cd0, ci0);  // token la15
        ins4(fmaf(-2.0f, acc[mt][1][r], eb), code, cd1, ci1);  // token la15+16
      }
    }
    // merge across the 4 row-groups sharing each token (xor 16, 32)
    merge4(cd0, ci0, 16); merge4(cd0, ci0, 32);
    merge4(cd1, ci1, 16); merge4(cd1, ci1, 32);

    if (lane < 16) {
      const int w32 = wv << 5;
#pragma unroll
      for (int s = 0; s < 4; ++s) {
        wcd[(w32 + lane) * 4 + s]      = cd0[s];
        wci[(w32 + lane) * 4 + s]      = ci0[s];
        wcd[(w32 + lane + 16) * 4 + s] = cd1[s];
        wci[(w32 + lane + 16) * 4 + s] = ci1[s];
      }
    }
    __syncthreads();

    // ---- global top-4-of-32 then faithful np-fp32 rescore ----
    if (tid < 128) {
      const int tok4 = tid >> 2, cnd = tid & 3;
      float fd[4]; int fi[4];
#pragma unroll
      for (int s = 0; s < 4; ++s) { fd[s] = 3.0e38f; fi[s] = 0x7fffffff; }
      for (int w2 = 0; w2 < 8; ++w2) {
#pragma unroll
        for (int s = 0; s < 4; ++s) {
          const int e = ((w2 << 5) + tok4) * 4 + s;
          ins4(wcd[e], wci[e], fd, fi);
        }
      }
      const int cme = fi[cnd];

      // rr: numpy pairwise sum of fl(r*r) over 512 (tree: ((pw+pw)+(pw+pw)))
      float blk;
      {
        const int kb = cnd * 128;
        float a[8];
#pragma unroll
        for (int j = 0; j < 8; ++j) {
          const float v = r_t[(kb + j) * MT + tok4];
          a[j] = __fmul_rn(v, v);
        }
        for (int i = 8; i < 128; i += 8) {
#pragma unroll
          for (int j = 0; j < 8; ++j) {
            const float v = r_t[(kb + i + j) * MT + tok4];
            a[j] = __fadd_rn(a[j], __fmul_rn(v, v));
          }
        }
        blk = __fadd_rn(__fadd_rn(__fadd_rn(a[0], a[1]), __fadd_rn(a[2], a[3])),
                        __fadd_rn(__fadd_rn(a[4], a[5]), __fadd_rn(a[6], a[7])));
      }
      const float pw256 = __fadd_rn(blk, __shfl_xor(blk, 1, 64));
      const float rr    = __fadd_rn(pw256, __shfl_xor(pw256, 2, 64));

      // cross: sgemm-faithful sequential-k FMA chain, K split at KSPLIT
      const float* ep = cbq + (size_t)cme * DDIM;
      float Sa = 0.f, Sb = 0.f;
      for (int kb = 0; kb < DDIM; kb += 8) {
        const float4 e0 = *(const float4*)(ep + kb);
        const float4 e1 = *(const float4*)(ep + kb + 4);
        const float ev[8] = {e0.x, e0.y, e0.z, e0.w, e1.x, e1.y, e1.z, e1.w};
        float rv[8];
#pragma unroll
        for (int j = 0; j < 8; ++j) rv[j] = r_t[(kb + j) * MT + tok4];
        if (kb < KSPLIT) {
#pragma unroll
          for (int j = 0; j < 8; ++j) Sa = __fmaf_rn(rv[j], ev[j], Sa);
        } else {
#pragma unroll
          for (int j = 0; j < 8; ++j) Sb = __fmaf_rn(rv[j], ev[j], Sb);
        }
      }
      const float cross = __fadd_rn(Sa, Sb);
      const float u = __fsub_rn(rr, __fmul_rn(2.0f, cross));
      float dW = __fadd_rn(u, enq[cme]);
      int   cW = cme;
#pragma unroll
      for (int m = 1; m <= 2; m <<= 1) {
        const float od = __shfl_xor(dW, m, 64);
        const int   oc = __shfl_xor(cW, m, 64);
        if (better(od, oc, dW, cW)) { dW = od; cW = oc; }
      }
      if (cnd == 0) {
        hist[tok4][qi] = cW;
        outidx[(size_t)(blockTok + tok4) * NQ + qi] = (float)cW;
      }
    }
    __syncthreads();

    // ---- faithful fp32 residual update + commit-loss sum ----
    // (tok = tid&31, kslab = tid>>5): 32-lane phase groups hit 32 distinct
    // LDS banks -> conflict-free; each thread owns a contiguous 32-k slab.
    {
      const int utok = tid & 31;
      const int ks   = tid >> 5;                      // 0..15
      const int wc = hist[utok][qi];
      const float* ew = cbq + (size_t)wc * DDIM + (ks << 5);
      double lssq = 0.0;
#pragma unroll
      for (int i = 0; i < 8; ++i) {
        const float4 qv = *(const float4*)(ew + (i << 2));
        const float qa[4] = {qv.x, qv.y, qv.z, qv.w};
        const int k0 = (ks << 5) + (i << 2);
#pragma unroll
        for (int e = 0; e < 4; ++e) {
          const float r  = r_t[(k0 + e) * MT + utok];
          const float a  = __fsub_rn(qa[e], r);       // fl(q - r)   (commit diff)
          const float qs = __fadd_rn(r, a);           // q_st = fl(r + (q-r))
          const float rn = __fsub_rn(r, qs);          // r' = fl(r - q_st)
          r_t[(k0 + e) * MT + utok] = rn;
          lssq += (double)a * (double)a;
        }
      }
#pragma unroll
      for (int off = 32; off; off >>= 1) lssq += __shfl_down(lssq, off, 64);
      if ((tid & 63) == 0) wred[tid >> 6] = lssq;
    }
    __syncthreads();
    if (tid == 0) {
      double s = 0.0;
#pragma unroll
      for (int w = 0; w < 8; ++w) s += wred[w];
      atomicAdd(&lossAcc[qi], s);
    }
  } // qi

  // ---- final: faithful fp32 replay -> quantized_out = sum of q_st per round ----
  {
    const int tokR = tid >> 4;          // 0..31
    const int part = tid & 15;          // 1/16 slice of D (coalesced global access)
#pragma unroll
    for (int i = 0; i < 8; ++i) {
      const int d4 = (part + i * 16) << 2;
      const float4 xv = *(const float4*)(x + (size_t)(blockTok + tokR) * DDIM + d4);
      float r[4]  = {xv.x, xv.y, xv.z, xv.w};
      float qa[4] = {0.f, 0.f, 0.f, 0.f};
#pragma unroll
      for (int j = 0; j < NQ; ++j) {
        const int hj = hist[tokR][j];
        const float4 ev = *(const float4*)(cb + ((size_t)j * NCODES + hj) * DDIM + d4);
        const float qv[4] = {ev.x, ev.y, ev.z, ev.w};
#pragma unroll
        for (int e = 0; e < 4; ++e) {
          const float a  = __fsub_rn(qv[e], r[e]);
          const float qs = __fadd_rn(r[e], a);
          r[e]  = __fsub_rn(r[e], qs);
          qa[e] = __fadd_rn(qa[e], qs);
        }
      }
      float4 pk; pk.x = qa[0]; pk.y = qa[1]; pk.z = qa[2]; pk.w = qa[3];
      *(float4*)(outq + (size_t)(blockTok + tokR) * DDIM + d4) = pk;
    }
  }
}

// ---------------- losses finalize ----------------
__global__ void loss_fin(const double* __restrict__ lossAcc,
                         float* __restrict__ outLoss,
                         float* __restrict__ outTot) {
  if (threadIdx.x == 0 && blockIdx.x == 0) {
    double tot = 0.0;
    for (int qi = 0; qi < NQ; ++qi) {
      const double v = lossAcc[qi] * (COMMIT_W / ((double)TOKENS * (double)DDIM));
      outLoss[qi] = (float)v;
      tot += v;
    }
    *outTot = (float)tot;
  }
}

extern "C" void kernel_launch(void* const* d_in, const int* in_sizes, int n_in,
                              void* d_out, int out_size, void* d_ws, size_t ws_size,
                              hipStream_t stream) {
  const float* x  = (const float*)d_in[0];
  const float* cb = (const float*)d_in[1];
  float* out = (float*)d_out;

  // workspace layout: [0..64) lossAcc f64 x8 | [256..33024) eef | [64K..64K+8M) f16 codebook
  double* lossAcc = (double*)d_ws;
  float*  eef     = (float*)((char*)d_ws + 256);
  f16*    cbH     = (f16*)((char*)d_ws + 65536);

  prep_kernel<<<dim3(32), dim3(256), 0, stream>>>(cb, eef, lossAcc);
  cvt_kernel<<<dim3(2048), dim3(256), 0, stream>>>(cb, cbH);
  rvq_main<<<dim3(NBLOCKS), dim3(NT), 0, stream>>>(x, cb, cbH, eef, lossAcc,
                                                   out, out + OFF_IDX);
  loss_fin<<<dim3(1), dim3(64), 0, stream>>>(lossAcc, out + OFF_LOSS, out + OFF_TOT);
}